// Round 12
// baseline (261.746 us; speedup 1.0000x reference)
//
#include <hip/hip_runtime.h>
#include <hip/hip_bf16.h>
#include <math.h>

#define B 32
#define S 4096
#define H 16
#define QC 1536
#define LORA 512
#define ROPE 64
#define NOPE 128
#define VH 128
#define DM 2048
#define NC 32          // chunks per batch for flash split-K
#define CHUNK (S / NC) // 128 rows per chunk
#define TR 4           // rows per staged LDS tile (18.5 KB LDS -> 8 blocks/CU)
#define NT (CHUNK / TR)
#define NKS 24         // k-slices for proj1 split-K (1536/64)

__device__ __constant__ float SCALE_C = 0.07216878364870323f; // 1/sqrt(192)

// ---------------- Kernel 1a: proj partials. grid (NKS=24, 12 col-slices), 256 thr.
__global__ __launch_bounds__(256) void k_proj_part(
    const float* __restrict__ q_c, const float* __restrict__ W_UQ,
    const float* __restrict__ W_QR, float* __restrict__ part) {
    const int ks = blockIdx.x, cs = blockIdx.y, t = threadIdx.x;
    const int k0 = ks * 64;
    __shared__ float qs[64][32]; // [k][b]
    for (int i = t; i < 64 * 32; i += 256) {
        const int k = i >> 5, b2 = i & 31;
        qs[k][b2] = q_c[(size_t)b2 * QC + k0 + k];
    }
    __syncthreads();
    const int tc = t & 63, tb = t >> 6;
    const int col = cs * 256 + tc * 4;
    const float* W; int N, coll;
    if (cs < 8) { W = W_UQ; N = 2048; coll = col; }
    else        { W = W_QR; N = 1024; coll = col - 2048; }
    float4 acc[8];
#pragma unroll
    for (int i = 0; i < 8; i++) acc[i] = make_float4(0.f, 0.f, 0.f, 0.f);
#pragma unroll 4
    for (int k = 0; k < 64; ++k) {
        const float4 w4 = *(const float4*)(W + (size_t)(k0 + k) * N + coll);
        const float4 a1 = *(const float4*)&qs[k][tb * 8];
        const float4 a2 = *(const float4*)&qs[k][tb * 8 + 4];
        acc[0].x += a1.x * w4.x; acc[0].y += a1.x * w4.y; acc[0].z += a1.x * w4.z; acc[0].w += a1.x * w4.w;
        acc[1].x += a1.y * w4.x; acc[1].y += a1.y * w4.y; acc[1].z += a1.y * w4.z; acc[1].w += a1.y * w4.w;
        acc[2].x += a1.z * w4.x; acc[2].y += a1.z * w4.y; acc[2].z += a1.z * w4.z; acc[2].w += a1.z * w4.w;
        acc[3].x += a1.w * w4.x; acc[3].y += a1.w * w4.y; acc[3].z += a1.w * w4.z; acc[3].w += a1.w * w4.w;
        acc[4].x += a2.x * w4.x; acc[4].y += a2.x * w4.y; acc[4].z += a2.x * w4.z; acc[4].w += a2.x * w4.w;
        acc[5].x += a2.y * w4.x; acc[5].y += a2.y * w4.y; acc[5].z += a2.y * w4.z; acc[5].w += a2.y * w4.w;
        acc[6].x += a2.z * w4.x; acc[6].y += a2.z * w4.y; acc[6].z += a2.z * w4.z; acc[6].w += a2.z * w4.w;
        acc[7].x += a2.w * w4.x; acc[7].y += a2.w * w4.y; acc[7].z += a2.w * w4.z; acc[7].w += a2.w * w4.w;
    }
#pragma unroll
    for (int j = 0; j < 8; j++) {
        const int b2 = tb * 8 + j;
        *(float4*)(part + ((size_t)ks * 32 + b2) * 3072 + col) = acc[j];
    }
}

// ---------------- Kernel 1b: fused reduce(24 partials) + RoPE.
// blocks 0..63: q_t reduce; 64..79: qr reduce + rope -> q_pe; 80: kpe_rot.
__global__ __launch_bounds__(256) void k_finalize(
    const float* __restrict__ part, const float* __restrict__ k_pe,
    const int* __restrict__ pos_arr, float* __restrict__ q_t,
    float* __restrict__ q_pe, float* __restrict__ kpe_rot) {
    const int blk = blockIdx.x, t = threadIdx.x;
    if (blk < 64) {
        const int idx = blk * 256 + t;       // 16384 float4s of q_t
        const int b = idx >> 9, c4 = idx & 511;
        const int col = c4 * 4;
        float4 acc = make_float4(0.f, 0.f, 0.f, 0.f);
        for (int ks = 0; ks < NKS; ks++) {
            const float4 p = *(const float4*)(part + ((size_t)ks * 32 + b) * 3072 + col);
            acc.x += p.x; acc.y += p.y; acc.z += p.z; acc.w += p.w;
        }
        *(float4*)(q_t + (size_t)b * 2048 + col) = acc;
    } else if (blk < 80) {
        const int idx = (blk - 64) * 256 + t; // 4096: b(32) x h(16) x pair(8)
        const int b = idx >> 7, rest = idx & 127;
        const int h = rest >> 3, pr = rest & 7;
        const int col1 = 2048 + h * 64 + pr * 4;
        float x1[4] = {0.f, 0.f, 0.f, 0.f}, x2[4] = {0.f, 0.f, 0.f, 0.f};
        for (int ks = 0; ks < NKS; ks++) {
            const float* p = part + ((size_t)ks * 32 + b) * 3072;
            const float4 a = *(const float4*)(p + col1);
            const float4 c = *(const float4*)(p + col1 + 32);
            x1[0] += a.x; x1[1] += a.y; x1[2] += a.z; x1[3] += a.w;
            x2[0] += c.x; x2[1] += c.y; x2[2] += c.z; x2[3] += c.w;
        }
        const int pos = pos_arr[b];
        float o1[4], o2[4];
#pragma unroll
        for (int e = 0; e < 4; ++e) {
            const int j = pr * 4 + e;
            const double inv = pow(10000.0, -(double)j / 32.0);
            const double f = (double)pos * inv;
            const float cc = (float)cos(f), ss = (float)sin(f);
            o1[e] = x1[e] * cc - x2[e] * ss;
            o2[e] = x2[e] * cc + x1[e] * ss;
        }
        float* qp = q_pe + (size_t)b * 1024 + h * 64 + pr * 4;
        *(float4*)qp = make_float4(o1[0], o1[1], o1[2], o1[3]);
        *(float4*)(qp + 32) = make_float4(o2[0], o2[1], o2[2], o2[3]);
    } else {
        for (int i = t; i < 32 * 32; i += 256) {
            const int b = i >> 5, j = i & 31;
            const int pos = pos_arr[b];
            const double inv = pow(10000.0, -(double)j / 32.0);
            const double f = (double)pos * inv;
            const float cc = (float)cos(f), ss = (float)sin(f);
            const float x1 = k_pe[(size_t)b * 64 + j], x2 = k_pe[(size_t)b * 64 + j + 32];
            kpe_rot[(size_t)b * 64 + j] = x1 * cc - x2 * ss;
            kpe_rot[(size_t)b * 64 + j + 32] = x2 * cc + x1 * ss;
        }
    }
}

// ---------------- Kernel 3: q_nope[b,h,l] = sum_n q_t[b,h,n] * W_UK[l,h,n]
// grid (8 l-slices, 16 heads); ALL 32 batches staged -> W_UK read exactly once.
__global__ __launch_bounds__(256) void k_qnope(
    const float* __restrict__ q_t, const float* __restrict__ W_UK,
    float* __restrict__ q_nope) {
    const int l0 = blockIdx.x * 64, h = blockIdx.y;
    const int t = threadIdx.x;
    __shared__ float qs[32][NOPE]; // 16 KB
    for (int i = t; i < 32 * NOPE; i += 256) {
        const int b2 = i >> 7, n = i & 127;
        qs[b2][n] = q_t[(size_t)b2 * 2048 + h * NOPE + n];
    }
    __syncthreads();
    const int wave = t >> 6, lane = t & 63;
    const int half = lane >> 5, nl = (lane & 31) * 4;
    for (int sw = 0; sw < 8; ++sw) {
        const int l = l0 + sw * 8 + wave * 2 + half;
        const float4 w4 = *(const float4*)(W_UK + ((size_t)l * H + h) * NOPE + nl);
        for (int b2 = 0; b2 < 32; ++b2) {
            const float4 a4 = *(const float4*)&qs[b2][nl];
            float d = a4.x * w4.x + a4.y * w4.y + a4.z * w4.z + a4.w * w4.w;
            d += __shfl_xor(d, 16);
            d += __shfl_xor(d, 8);
            d += __shfl_xor(d, 4);
            d += __shfl_xor(d, 2);
            d += __shfl_xor(d, 1);
            if ((lane & 31) == 0)
                q_nope[((size_t)b2 * H + h) * LORA + l] = d;
        }
    }
}

// ---------------- Kernel 4: flash decode, LDS double-buffered via global_load_lds
// R7 structure with TR=4: 128 thr = 2 waves = 8 groups of 16 lanes; group g owns
// heads 2g,2g+1. 18.5 KB LDS -> 8 blocks/CU (double R7's occupancy).
// Defer-max online softmax (THR=8). 4-level within-16 DPP reduce.
__global__ __launch_bounds__(128) void k_flash(
    const float* __restrict__ q_nope, const float* __restrict__ q_pe,
    const float* __restrict__ kv_cache, const float* __restrict__ kpe_cache,
    const float* __restrict__ k_c_normed, const float* __restrict__ kpe_rot,
    const int* __restrict__ pos_arr, float* __restrict__ part_o,
    float* __restrict__ part_ml) {
    __shared__ float lds_kv[2][TR][LORA]; // 16 KB
    __shared__ float lds_pe[2][TR][ROPE]; //  2 KB
    const int blk = blockIdx.x;
    const int b = blk / NC, c = blk % NC;
    const int t = threadIdx.x;
    const int g = t >> 4, j = t & 15;     // 8 groups of 16
    const int wave = t >> 6, lane = t & 63;
    const int pos = pos_arr[b];
    const int s0 = c * CHUNK;
    const int rel = pos - s0;
    const int ptile = (rel >= 0 && rel < CHUNK) ? (rel / TR) : -1;

    const char* kvg = (const char*)kv_cache + (size_t)b * S * LORA * 4;
    const char* peg = (const char*)kpe_cache + (size_t)b * S * ROPE * 4;
    const float* kc_b = k_c_normed + (size_t)b * LORA;
    const float* kr_b = kpe_rot + (size_t)b * ROPE;

    const int wo = wave * 1024 + lane * 16;

    auto stage = [&](int bi, int tile) {
        // kv tile: TR*LORA*4 = 8192 B; 2 waves x 4 insts x 1024 B
        const char* gk = kvg + (size_t)(s0 + tile * TR) * (LORA * 4);
        char* lk = (char*)&lds_kv[bi][0][0];
#pragma unroll
        for (int i = 0; i < 4; ++i) {
            __builtin_amdgcn_global_load_lds(
                (const __attribute__((address_space(1))) void*)(gk + i * 2048 + wo),
                (__attribute__((address_space(3))) void*)(lk + i * 2048 + wave * 1024),
                16, 0, 0);
        }
        // pe tile: TR*ROPE*4 = 1024 B; wave 0 only
        if (t < 64) {
            const char* gp = peg + (size_t)(s0 + tile * TR) * (ROPE * 4);
            char* lp = (char*)&lds_pe[bi][0][0];
            __builtin_amdgcn_global_load_lds(
                (const __attribute__((address_space(1))) void*)(gp + lane * 16),
                (__attribute__((address_space(3))) void*)(lp + lane * 16),
                16, 0, 0);
        }
    };
    auto patch = [&](int bi, int prow) {
        ((float4*)&lds_kv[bi][prow][0])[t] = ((const float4*)kc_b)[t];
        if (t < 16)
            ((float4*)&lds_pe[bi][prow][0])[t] = ((const float4*)kr_b)[t];
    };

    // q fragments for this group's 2 heads, this lane's dim chunk
    float4 q4[2][9];
#pragma unroll
    for (int h = 0; h < 2; ++h) {
        const float* qn = q_nope + ((size_t)b * H + 2 * g + h) * LORA;
#pragma unroll
        for (int k = 0; k < 8; k++) q4[h][k] = *(const float4*)(qn + 4 * j + 64 * k);
        q4[h][8] = *(const float4*)(q_pe + ((size_t)b * H + 2 * g + h) * 64 + 4 * j);
    }

    float m_run[2] = {-INFINITY, -INFINITY}, l_run[2] = {0.f, 0.f};
    float4 o_acc[2][8];
#pragma unroll
    for (int h = 0; h < 2; ++h)
#pragma unroll
        for (int k = 0; k < 8; k++) o_acc[h][k] = make_float4(0.f, 0.f, 0.f, 0.f);

    stage(0, 0);
    asm volatile("s_waitcnt vmcnt(0)" ::: "memory");
    __syncthreads();
    if (ptile == 0) { patch(0, rel); __syncthreads(); }

    int cur = 0;
    for (int tile = 0; tile < NT; ++tile) {
        if (tile + 1 < NT) stage(cur ^ 1, tile + 1);

        for (int r = 0; r < TR; ++r) {
            const float* kvr = &lds_kv[cur][r][0];
            float4 kv4[8];
#pragma unroll
            for (int k = 0; k < 8; k++) kv4[k] = *(const float4*)(kvr + 4 * j + 64 * k);
            float4 p4 = *(const float4*)(&lds_pe[cur][r][0] + 4 * j);

            float sc[2];
#pragma unroll
            for (int h = 0; h < 2; ++h) {
                float acc = 0.f;
#pragma unroll
                for (int k = 0; k < 8; k++)
                    acc += q4[h][k].x * kv4[k].x + q4[h][k].y * kv4[k].y +
                           q4[h][k].z * kv4[k].z + q4[h][k].w * kv4[k].w;
                acc += q4[h][8].x * p4.x + q4[h][8].y * p4.y +
                       q4[h][8].z * p4.z + q4[h][8].w * p4.w;
                sc[h] = acc;
            }
            // 4-level within-16 DPP reduce for both heads
#pragma unroll
            for (int msk = 8; msk >= 1; msk >>= 1) {
                sc[0] += __shfl_xor(sc[0], msk);
                sc[1] += __shfl_xor(sc[1], msk);
            }
#pragma unroll
            for (int h = 0; h < 2; ++h) {
                const float s = sc[h] * SCALE_C;
                if (s > m_run[h] + 8.0f) { // defer-max rescale
                    const float alpha = __expf(m_run[h] - s); // exp(-inf)=0 first hit
                    l_run[h] *= alpha;
#pragma unroll
                    for (int k = 0; k < 8; k++) {
                        o_acc[h][k].x *= alpha; o_acc[h][k].y *= alpha;
                        o_acc[h][k].z *= alpha; o_acc[h][k].w *= alpha;
                    }
                    m_run[h] = s;
                }
                const float p = __expf(s - m_run[h]); // bounded by e^8
                l_run[h] += p;
#pragma unroll
                for (int k = 0; k < 8; k++) {
                    o_acc[h][k].x += p * kv4[k].x; o_acc[h][k].y += p * kv4[k].y;
                    o_acc[h][k].z += p * kv4[k].z; o_acc[h][k].w += p * kv4[k].w;
                }
            }
        }

        asm volatile("s_waitcnt vmcnt(0)" ::: "memory");
        __syncthreads();
        if (tile + 1 < NT && ptile == tile + 1) {
            patch(cur ^ 1, rel - ptile * TR);
            __syncthreads();
        }
        cur ^= 1;
    }

    float* po = part_o + (((size_t)b * NC + c) * H) * LORA;
#pragma unroll
    for (int h = 0; h < 2; ++h) {
        float* p = po + (size_t)(2 * g + h) * LORA;
#pragma unroll
        for (int k = 0; k < 8; k++) *(float4*)(p + 4 * j + 64 * k) = o_acc[h][k];
    }
    if (j == 0) {
        float* pml = part_ml + (((size_t)b * NC + c) * H + 2 * g) * 2;
        pml[0] = m_run[0]; pml[1] = l_run[0];
        pml[2] = m_run[1]; pml[3] = l_run[1];
    }
}

// ---------------- Kernel 5: combine partials -> o (LDS), fused v = o . W_UV
__global__ __launch_bounds__(256) void k_combine(
    const float* __restrict__ part_o, const float* __restrict__ part_ml,
    const float* __restrict__ W_UV, float* __restrict__ v) {
    const int b0 = blockIdx.x * 4, h = blockIdx.y, t = threadIdx.x;
    __shared__ float ml_s[4][NC][2];
    __shared__ float o_s[4][LORA]; // 8 KB
    if (t < 256) {
        const int b2 = t >> 6, c = (t >> 1) & 31, w = t & 1;
        ml_s[b2][c][w] = part_ml[(((size_t)(b0 + b2) * NC + c) * H + h) * 2 + w];
    }
    __syncthreads();
    float m_b[4], inv_l[4];
#pragma unroll
    for (int b2 = 0; b2 < 4; ++b2) {
        float m = -INFINITY;
        for (int c = 0; c < NC; c++) m = fmaxf(m, ml_s[b2][c][0]);
        float l = 0.f;
        for (int c = 0; c < NC; c++) l += ml_s[b2][c][1] * __expf(ml_s[b2][c][0] - m);
        m_b[b2] = m;
        inv_l[b2] = 1.0f / l;
    }
    for (int i = t; i < 4 * LORA; i += 256) {
        const int b2 = i >> 9, li = i & 511;
        float acc = 0.f;
        for (int c = 0; c < NC; c++) {
            acc += part_o[(((size_t)(b0 + b2) * NC + c) * H + h) * LORA + li] *
                   __expf(ml_s[b2][c][0] - m_b[b2]);
        }
        o_s[b2][li] = acc * inv_l[b2];
    }
    __syncthreads();
    const int vi = t & 127, bp = t >> 7;
    float acc0 = 0.f, acc1 = 0.f;
    for (int l = 0; l < LORA; l += 4) {
        const float w0 = W_UV[(size_t)(l + 0) * (H * VH) + h * VH + vi];
        const float w1 = W_UV[(size_t)(l + 1) * (H * VH) + h * VH + vi];
        const float w2 = W_UV[(size_t)(l + 2) * (H * VH) + h * VH + vi];
        const float w3 = W_UV[(size_t)(l + 3) * (H * VH) + h * VH + vi];
        const float4 oa = *(const float4*)&o_s[bp * 2][l];
        const float4 ob = *(const float4*)&o_s[bp * 2 + 1][l];
        acc0 += oa.x * w0 + oa.y * w1 + oa.z * w2 + oa.w * w3;
        acc1 += ob.x * w0 + ob.y * w1 + ob.z * w2 + ob.w * w3;
    }
    v[(size_t)(b0 + bp * 2) * (H * VH) + h * VH + vi] = acc0;
    v[(size_t)(b0 + bp * 2 + 1) * (H * VH) + h * VH + vi] = acc1;
}

// ---------------- Kernel 6: out_part[ks] = V[:, k-slice] @ W_O[k-slice, :]
__global__ void k_out(const float* __restrict__ v, const float* __restrict__ W_O,
                      float* __restrict__ out_part) {
    const int dsl = blockIdx.x, ksl = blockIdx.y, t = threadIdx.x;
    const int d0 = dsl * 128, k0 = ksl * 128;
    __shared__ float vs[32][128];
    for (int i = t; i < 32 * 128; i += 256) {
        const int bi = i >> 7, kk = i & 127;
        vs[bi][kk] = v[(size_t)bi * DM + k0 + kk];
    }
    __syncthreads();
    const int dl = t & 127, bh = t >> 7;
    float acc[16];
#pragma unroll
    for (int i = 0; i < 16; i++) acc[i] = 0.f;
    for (int kk = 0; kk < 128; kk += 4) {
        const float w0 = W_O[(size_t)(k0 + kk + 0) * DM + d0 + dl];
        const float w1 = W_O[(size_t)(k0 + kk + 1) * DM + d0 + dl];
        const float w2 = W_O[(size_t)(k0 + kk + 2) * DM + d0 + dl];
        const float w3 = W_O[(size_t)(k0 + kk + 3) * DM + d0 + dl];
#pragma unroll
        for (int i = 0; i < 16; i++) {
            const float4 vv = *(const float4*)&vs[bh * 16 + i][kk];
            acc[i] += vv.x * w0 + vv.y * w1 + vv.z * w2 + vv.w * w3;
        }
    }
    float* op = out_part + (size_t)ksl * 32 * DM;
#pragma unroll
    for (int i = 0; i < 16; i++) op[(size_t)(bh * 16 + i) * DM + d0 + dl] = acc[i];
}

// ---------------- Kernel 7: reduce the 16 split-K partials
__global__ void k_out_reduce(const float* __restrict__ out_part, float* __restrict__ out) {
    const int idx = blockIdx.x * 256 + threadIdx.x;
    float4 acc = make_float4(0.f, 0.f, 0.f, 0.f);
    for (int ks = 0; ks < 16; ks++) {
        float4 p = *(const float4*)(out_part + (size_t)ks * (32 * DM) + (size_t)idx * 4);
        acc.x += p.x; acc.y += p.y; acc.z += p.z; acc.w += p.w;
    }
    *(float4*)(out + (size_t)idx * 4) = acc;
}

extern "C" void kernel_launch(void* const* d_in, const int* in_sizes, int n_in,
                              void* d_out, int out_size, void* d_ws, size_t ws_size,
                              hipStream_t stream) {
    const float* q_c        = (const float*)d_in[0];
    const float* k_c_normed = (const float*)d_in[1];
    const float* k_pe       = (const float*)d_in[2];
    const float* kv_c_cache = (const float*)d_in[3];
    const float* k_pe_cache = (const float*)d_in[4];
    const float* W_UQ       = (const float*)d_in[5];
    const float* W_UK       = (const float*)d_in[6];
    const float* W_QR       = (const float*)d_in[7];
    const float* W_UV       = (const float*)d_in[8];
    const float* W_O        = (const float*)d_in[9];
    const int*   pos        = (const int*)d_in[10];

    float* ws = (float*)d_ws;
    float* q_t      = ws;                       // 65536
    float* qr_unused= q_t + 65536;              // 32768 (kept for layout stability)
    float* q_pe     = qr_unused + 32768;        // 32768
    float* kpe_rot  = q_pe + 32768;             // 2048
    float* q_nope   = kpe_rot + 2048;           // 262144
    float* part_o   = q_nope + 262144;          // 8388608
    float* part_ml  = part_o + (size_t)B * NC * H * LORA;   // 32768
    float* v        = part_ml + (size_t)B * NC * H * 2;     // 65536
    float* out_part = v + 65536;                // 1048576
    float* proj_part = out_part + (size_t)16 * 32 * DM;     // 2359296

    k_proj_part<<<dim3(NKS, 12), 256, 0, stream>>>(q_c, W_UQ, W_QR, proj_part);
    k_finalize<<<81, 256, 0, stream>>>(proj_part, k_pe, pos, q_t, q_pe, kpe_rot);
    k_qnope<<<dim3(8, 16), 256, 0, stream>>>(q_t, W_UK, q_nope);
    k_flash<<<B * NC, 128, 0, stream>>>(q_nope, q_pe, kv_c_cache, k_pe_cache,
                                        k_c_normed, kpe_rot, pos, part_o, part_ml);
    k_combine<<<dim3(8, 16), 256, 0, stream>>>(part_o, part_ml, W_UV, v);
    k_out<<<dim3(16, 16), 256, 0, stream>>>(v, W_O, out_part);
    k_out_reduce<<<64, 256, 0, stream>>>(out_part, (float*)d_out);
}

// Round 13
// 226.438 us; speedup vs baseline: 1.1559x; 1.1559x over previous
//
#include <hip/hip_runtime.h>
#include <hip/hip_bf16.h>
#include <math.h>

#define B 32
#define S 4096
#define H 16
#define QC 1536
#define LORA 512
#define ROPE 64
#define NOPE 128
#define VH 128
#define DM 2048
#define NC 32          // chunks per batch for flash split-K
#define CHUNK (S / NC) // 128 rows per chunk
#define NKS 24         // k-slices for proj1 split-K (1536/64)
#define FLP 584        // flash LDS row pitch in bf16 (b128-aligned, 2-way-free banks)

__device__ __constant__ float SCALE_C = 0.07216878364870323f; // 1/sqrt(192)

typedef __attribute__((ext_vector_type(8))) short bf16x8;
typedef __attribute__((ext_vector_type(4))) float f32x4;

__device__ inline ushort f2b(float x) { // fp32 -> bf16 RNE
    union { float f; uint u; } v; v.f = x;
    return (ushort)((v.u + 0x7FFFu + ((v.u >> 16) & 1u)) >> 16);
}

// ---------------- Kernel 1a: proj partials. grid (NKS=24, 12 col-slices), 256 thr.
__global__ __launch_bounds__(256) void k_proj_part(
    const float* __restrict__ q_c, const float* __restrict__ W_UQ,
    const float* __restrict__ W_QR, float* __restrict__ part) {
    const int ks = blockIdx.x, cs = blockIdx.y, t = threadIdx.x;
    const int k0 = ks * 64;
    __shared__ float qs[64][32]; // [k][b]
    for (int i = t; i < 64 * 32; i += 256) {
        const int k = i >> 5, b2 = i & 31;
        qs[k][b2] = q_c[(size_t)b2 * QC + k0 + k];
    }
    __syncthreads();
    const int tc = t & 63, tb = t >> 6;
    const int col = cs * 256 + tc * 4;
    const float* W; int N, coll;
    if (cs < 8) { W = W_UQ; N = 2048; coll = col; }
    else        { W = W_QR; N = 1024; coll = col - 2048; }
    float4 acc[8];
#pragma unroll
    for (int i = 0; i < 8; i++) acc[i] = make_float4(0.f, 0.f, 0.f, 0.f);
#pragma unroll 4
    for (int k = 0; k < 64; ++k) {
        const float4 w4 = *(const float4*)(W + (size_t)(k0 + k) * N + coll);
        const float4 a1 = *(const float4*)&qs[k][tb * 8];
        const float4 a2 = *(const float4*)&qs[k][tb * 8 + 4];
        acc[0].x += a1.x * w4.x; acc[0].y += a1.x * w4.y; acc[0].z += a1.x * w4.z; acc[0].w += a1.x * w4.w;
        acc[1].x += a1.y * w4.x; acc[1].y += a1.y * w4.y; acc[1].z += a1.y * w4.z; acc[1].w += a1.y * w4.w;
        acc[2].x += a1.z * w4.x; acc[2].y += a1.z * w4.y; acc[2].z += a1.z * w4.z; acc[2].w += a1.z * w4.w;
        acc[3].x += a1.w * w4.x; acc[3].y += a1.w * w4.y; acc[3].z += a1.w * w4.z; acc[3].w += a1.w * w4.w;
        acc[4].x += a2.x * w4.x; acc[4].y += a2.x * w4.y; acc[4].z += a2.x * w4.z; acc[4].w += a2.x * w4.w;
        acc[5].x += a2.y * w4.x; acc[5].y += a2.y * w4.y; acc[5].z += a2.y * w4.z; acc[5].w += a2.y * w4.w;
        acc[6].x += a2.z * w4.x; acc[6].y += a2.z * w4.y; acc[6].z += a2.z * w4.z; acc[6].w += a2.z * w4.w;
        acc[7].x += a2.w * w4.x; acc[7].y += a2.w * w4.y; acc[7].z += a2.w * w4.z; acc[7].w += a2.w * w4.w;
    }
#pragma unroll
    for (int j = 0; j < 8; j++) {
        const int b2 = tb * 8 + j;
        *(float4*)(part + ((size_t)ks * 32 + b2) * 3072 + col) = acc[j];
    }
}

// ---------------- Kernel 1b: fused reduce(24 partials) + RoPE.
// blocks 0..63: q_t reduce; 64..79: qr reduce + rope -> q_bf[...,512..575] (bf16);
// 80: kpe_rot (f32).
__global__ __launch_bounds__(256) void k_finalize(
    const float* __restrict__ part, const float* __restrict__ k_pe,
    const int* __restrict__ pos_arr, float* __restrict__ q_t,
    ushort* __restrict__ q_bf, float* __restrict__ kpe_rot) {
    const int blk = blockIdx.x, t = threadIdx.x;
    if (blk < 64) {
        const int idx = blk * 256 + t;
        const int b = idx >> 9, c4 = idx & 511;
        const int col = c4 * 4;
        float4 acc = make_float4(0.f, 0.f, 0.f, 0.f);
        for (int ks = 0; ks < NKS; ks++) {
            const float4 p = *(const float4*)(part + ((size_t)ks * 32 + b) * 3072 + col);
            acc.x += p.x; acc.y += p.y; acc.z += p.z; acc.w += p.w;
        }
        *(float4*)(q_t + (size_t)b * 2048 + col) = acc;
    } else if (blk < 80) {
        const int idx = (blk - 64) * 256 + t;
        const int b = idx >> 7, rest = idx & 127;
        const int h = rest >> 3, pr = rest & 7;
        const int col1 = 2048 + h * 64 + pr * 4;
        float x1[4] = {0.f, 0.f, 0.f, 0.f}, x2[4] = {0.f, 0.f, 0.f, 0.f};
        for (int ks = 0; ks < NKS; ks++) {
            const float* p = part + ((size_t)ks * 32 + b) * 3072;
            const float4 a = *(const float4*)(p + col1);
            const float4 c = *(const float4*)(p + col1 + 32);
            x1[0] += a.x; x1[1] += a.y; x1[2] += a.z; x1[3] += a.w;
            x2[0] += c.x; x2[1] += c.y; x2[2] += c.z; x2[3] += c.w;
        }
        const int pos = pos_arr[b];
        ushort* qb = q_bf + ((size_t)b * 16 + h) * 576 + 512 + pr * 4;
#pragma unroll
        for (int e = 0; e < 4; ++e) {
            const int j = pr * 4 + e;
            const double inv = pow(10000.0, -(double)j / 32.0);
            const double f = (double)pos * inv;
            const float cc = (float)cos(f), ss = (float)sin(f);
            qb[e] = f2b(x1[e] * cc - x2[e] * ss);
            qb[32 + e] = f2b(x2[e] * cc + x1[e] * ss);
        }
    } else {
        for (int i = t; i < 32 * 32; i += 256) {
            const int b = i >> 5, j = i & 31;
            const int pos = pos_arr[b];
            const double inv = pow(10000.0, -(double)j / 32.0);
            const double f = (double)pos * inv;
            const float cc = (float)cos(f), ss = (float)sin(f);
            const float x1 = k_pe[(size_t)b * 64 + j], x2 = k_pe[(size_t)b * 64 + j + 32];
            kpe_rot[(size_t)b * 64 + j] = x1 * cc - x2 * ss;
            kpe_rot[(size_t)b * 64 + j + 32] = x2 * cc + x1 * ss;
        }
    }
}

// ---------------- Kernel 3: q_bf[b,h,l] = bf16( sum_n q_t[b,h,n] * W_UK[l,h,n] )
__global__ __launch_bounds__(256) void k_qnope(
    const float* __restrict__ q_t, const float* __restrict__ W_UK,
    ushort* __restrict__ q_bf) {
    const int l0 = blockIdx.x * 64, h = blockIdx.y;
    const int t = threadIdx.x;
    __shared__ float qs[32][NOPE]; // 16 KB
    for (int i = t; i < 32 * NOPE; i += 256) {
        const int b2 = i >> 7, n = i & 127;
        qs[b2][n] = q_t[(size_t)b2 * 2048 + h * NOPE + n];
    }
    __syncthreads();
    const int wave = t >> 6, lane = t & 63;
    const int half = lane >> 5, nl = (lane & 31) * 4;
    for (int sw = 0; sw < 8; ++sw) {
        const int l = l0 + sw * 8 + wave * 2 + half;
        const float4 w4 = *(const float4*)(W_UK + ((size_t)l * H + h) * NOPE + nl);
        for (int b2 = 0; b2 < 32; ++b2) {
            const float4 a4 = *(const float4*)&qs[b2][nl];
            float d = a4.x * w4.x + a4.y * w4.y + a4.z * w4.z + a4.w * w4.w;
            d += __shfl_xor(d, 16);
            d += __shfl_xor(d, 8);
            d += __shfl_xor(d, 4);
            d += __shfl_xor(d, 2);
            d += __shfl_xor(d, 1);
            if ((lane & 31) == 0)
                q_bf[((size_t)b2 * 16 + h) * 576 + l] = f2b(d);
        }
    }
}

// ---------------- Kernel 4: MFMA flash decode (bf16 matrix cores)
// Block = 256 thr = 4 waves; one (b, 128-row chunk) per block.
// K-tiles of 16 rows staged global->reg->bf16->LDS [16][FLP], double-buffered.
// QK: mfma_16x16x32_bf16(A=K rows, B=Q) -> S[row][head]; online softmax
// (defer-max THR=8, per-head state in lanes hd=lane&15, shfl_xor 16/32 reduce).
// P transposed via wave-private LDS bounce (2 rows/u32) -> PV A-operand direct.
// PV every 2 tiles: mfma(A=P[head][row], B=V[row][dim]); wave owns 128-dim quarter.
__global__ __launch_bounds__(256) void k_flash(
    const ushort* __restrict__ q_bf, const float* __restrict__ kv_cache,
    const float* __restrict__ kpe_cache, const float* __restrict__ k_c_normed,
    const float* __restrict__ kpe_rot, const int* __restrict__ pos_arr,
    float* __restrict__ part_o, float* __restrict__ part_ml) {
    __shared__ ushort k_lds[2][16][FLP]; // 37376 B
    __shared__ uint p_lds[4][16][20];    //  5120 B (wave-private P bounce, padded)
    const int blk = blockIdx.x;
    const int b = blk / NC, c = blk % NC;
    const int t = threadIdx.x, lane = t & 63, wave = t >> 6;
    const int lg = lane >> 4, hd = lane & 15;
    const int pos = pos_arr[b];
    const int s0 = c * CHUNK;
    const int rel = pos - s0;
    const int pt = (rel >= 0 && rel < CHUNK) ? (rel >> 4) : -1;
    const int prow = rel & 15;

    const float* kv_b = kv_cache + (size_t)b * S * LORA;
    const float* kp_b = kpe_cache + (size_t)b * S * ROPE;
    const float* kc_b = k_c_normed + (size_t)b * LORA;
    const float* kr_b = kpe_rot + (size_t)b * ROPE;

    // Q fragments: head hd, dims 32*ks + lg*8 + i  (B-operand layout)
    bf16x8 qf[18];
    {
        const ushort* qr = q_bf + ((size_t)b * 16 + hd) * 576 + lg * 8;
#pragma unroll
        for (int ks = 0; ks < 18; ++ks)
            qf[ks] = *(const bf16x8*)(qr + 32 * ks);
    }

    float4 ld[9];
    auto issue = [&](int tile) { // global loads for tile into regs (issue-early)
        const int r = t >> 4, f0 = t & 15;
        const int s = s0 + tile * 16 + r;
        const float* kvr = kv_b + (size_t)s * LORA;
        const float* per = kp_b + (size_t)s * ROPE;
#pragma unroll
        for (int k = 0; k < 8; ++k) ld[k] = *(const float4*)(kvr + 4 * (f0 + 16 * k));
        ld[8] = *(const float4*)(per + 4 * f0);
    };
    auto wtile = [&](int buf) { // bf16-convert + LDS write (write-late)
        const int r = t >> 4, f0 = t & 15;
        ushort* dst = &k_lds[buf][r][0];
#pragma unroll
        for (int k = 0; k < 9; ++k) {
            const int f = f0 + 16 * k;
            ushort4 h4;
            h4.x = f2b(ld[k].x); h4.y = f2b(ld[k].y);
            h4.z = f2b(ld[k].z); h4.w = f2b(ld[k].w);
            *(ushort4*)(dst + 4 * f) = h4;
        }
    };
    auto patch = [&](int buf) { // replace pos-row with k_c_normed / kpe_rot
        if (t < 144) {
            const float4 v = (t < 128) ? *(const float4*)(kc_b + 4 * t)
                                       : *(const float4*)(kr_b + 4 * (t - 128));
            ushort4 h4;
            h4.x = f2b(v.x); h4.y = f2b(v.y); h4.z = f2b(v.z); h4.w = f2b(v.w);
            *(ushort4*)(&k_lds[buf][prow][4 * t]) = h4;
        }
    };

    f32x4 acc[8];
#pragma unroll
    for (int i = 0; i < 8; ++i) acc[i] = (f32x4){0.f, 0.f, 0.f, 0.f};
    float m_run = -INFINITY, l_run = 0.f;

    issue(0);
    wtile(0);
    if (pt == 0) patch(0);
    __syncthreads();

    for (int tt = 0; tt < 8; ++tt) {
        if (tt < 7) issue(tt + 1);

        // ---- QK^T for this 16-row tile
        f32x4 S4 = (f32x4){0.f, 0.f, 0.f, 0.f};
        {
            const ushort* krow = &k_lds[tt & 1][hd][lg * 8];
#pragma unroll
            for (int ks = 0; ks < 18; ++ks) {
                const bf16x8 av = *(const bf16x8*)(krow + 32 * ks);
                S4 = __builtin_amdgcn_mfma_f32_16x16x32_bf16(av, qf[ks], S4, 0, 0, 0);
            }
        }
        const float sc0 = S4[0] * SCALE_C, sc1 = S4[1] * SCALE_C;
        const float sc2 = S4[2] * SCALE_C, sc3 = S4[3] * SCALE_C;

        // ---- online softmax (per-head state lives in lanes with hd == head)
        float smax = fmaxf(fmaxf(sc0, sc1), fmaxf(sc2, sc3));
        smax = fmaxf(smax, __shfl_xor(smax, 16));
        smax = fmaxf(smax, __shfl_xor(smax, 32));
        const bool need = smax > m_run + 8.0f;
        if (__any(need)) {
            const float m_new = need ? smax : m_run;
            const float alpha = __expf(m_run - m_new); // 1 if !need; 0 on first hit
            l_run *= alpha;
            m_run = m_new;
            const int hb = lg * 4; // accumulator heads = hb+reg
            const float a0 = __shfl(alpha, hb + 0), a1 = __shfl(alpha, hb + 1);
            const float a2 = __shfl(alpha, hb + 2), a3 = __shfl(alpha, hb + 3);
#pragma unroll
            for (int d2 = 0; d2 < 8; ++d2) {
                acc[d2][0] *= a0; acc[d2][1] *= a1;
                acc[d2][2] *= a2; acc[d2][3] *= a3;
            }
        }
        const float p0 = __expf(sc0 - m_run), p1 = __expf(sc1 - m_run);
        const float p2 = __expf(sc2 - m_run), p3 = __expf(sc3 - m_run);
        float ps = p0 + p1 + p2 + p3;
        ps += __shfl_xor(ps, 16);
        ps += __shfl_xor(ps, 32);
        l_run += ps;
        // P bounce: u32 u holds rows {2u, 2u+1} (lo=even) for head hd
        const uint plo = (uint)f2b(p0) | ((uint)f2b(p1) << 16);
        const uint phi = (uint)f2b(p2) | ((uint)f2b(p3) << 16);
        *(uint2*)&p_lds[wave][hd][(tt & 1) * 8 + lg * 2] = make_uint2(plo, phi);

        // ---- PV over the 32 rows of tiles {tt-1, tt} (buffers 0,1)
        if (tt & 1) {
            const bf16x8 ap = *(const bf16x8*)&p_lds[wave][hd][lg * 4]; // rows 8lg..8lg+7
            const int half = lane >> 5;          // rows 0-15 -> buf0, 16-31 -> buf1
            const int rbase = (lg & 1) * 8;      // row-in-tile base
#pragma unroll
            for (int dt = 0; dt < 8; ++dt) {
                const int dcol = wave * 128 + dt * 16 + hd;
                union { bf16x8 v; ushort u[8]; } bv;
#pragma unroll
                for (int i2 = 0; i2 < 8; ++i2)
                    bv.u[i2] = k_lds[half][rbase + i2][dcol];
                acc[dt] = __builtin_amdgcn_mfma_f32_16x16x32_bf16(ap, bv.v, acc[dt], 0, 0, 0);
            }
        }

        __syncthreads(); // all waves done reading both buffers
        if (tt < 7) {
            wtile((tt + 1) & 1);
            if (pt == tt + 1) patch((tt + 1) & 1);
        }
        __syncthreads(); // next tile visible
    }

    // ---- epilogue: O[head = lg*4+reg][dim = wave*128 + dt*16 + hd]
    float* po = part_o + ((size_t)(b * NC + c) * H) * LORA;
#pragma unroll
    for (int dt = 0; dt < 8; ++dt) {
        const int dim = wave * 128 + dt * 16 + hd;
        const int hb = lg * 4;
        po[(size_t)(hb + 0) * LORA + dim] = acc[dt][0];
        po[(size_t)(hb + 1) * LORA + dim] = acc[dt][1];
        po[(size_t)(hb + 2) * LORA + dim] = acc[dt][2];
        po[(size_t)(hb + 3) * LORA + dim] = acc[dt][3];
    }
    if (wave == 0 && lane < 16) {
        float* pml = part_ml + ((size_t)(b * NC + c) * H + lane) * 2;
        pml[0] = m_run;
        pml[1] = l_run;
    }
}

// ---------------- Kernel 5: combine partials -> o (LDS), fused v = o . W_UV
__global__ __launch_bounds__(256) void k_combine(
    const float* __restrict__ part_o, const float* __restrict__ part_ml,
    const float* __restrict__ W_UV, float* __restrict__ v) {
    const int b0 = blockIdx.x * 4, h = blockIdx.y, t = threadIdx.x;
    __shared__ float ml_s[4][NC][2];
    __shared__ float o_s[4][LORA]; // 8 KB
    if (t < 256) {
        const int b2 = t >> 6, c = (t >> 1) & 31, w = t & 1;
        ml_s[b2][c][w] = part_ml[(((size_t)(b0 + b2) * NC + c) * H + h) * 2 + w];
    }
    __syncthreads();
    float m_b[4], inv_l[4];
#pragma unroll
    for (int b2 = 0; b2 < 4; ++b2) {
        float m = -INFINITY;
        for (int c = 0; c < NC; c++) m = fmaxf(m, ml_s[b2][c][0]);
        float l = 0.f;
        for (int c = 0; c < NC; c++) l += ml_s[b2][c][1] * __expf(ml_s[b2][c][0] - m);
        m_b[b2] = m;
        inv_l[b2] = 1.0f / l;
    }
    for (int i = t; i < 4 * LORA; i += 256) {
        const int b2 = i >> 9, li = i & 511;
        float acc = 0.f;
        for (int c = 0; c < NC; c++) {
            acc += part_o[(((size_t)(b0 + b2) * NC + c) * H + h) * LORA + li] *
                   __expf(ml_s[b2][c][0] - m_b[b2]);
        }
        o_s[b2][li] = acc * inv_l[b2];
    }
    __syncthreads();
    const int vi = t & 127, bp = t >> 7;
    float acc0 = 0.f, acc1 = 0.f;
    for (int l = 0; l < LORA; l += 4) {
        const float w0 = W_UV[(size_t)(l + 0) * (H * VH) + h * VH + vi];
        const float w1 = W_UV[(size_t)(l + 1) * (H * VH) + h * VH + vi];
        const float w2 = W_UV[(size_t)(l + 2) * (H * VH) + h * VH + vi];
        const float w3 = W_UV[(size_t)(l + 3) * (H * VH) + h * VH + vi];
        const float4 oa = *(const float4*)&o_s[bp * 2][l];
        const float4 ob = *(const float4*)&o_s[bp * 2 + 1][l];
        acc0 += oa.x * w0 + oa.y * w1 + oa.z * w2 + oa.w * w3;
        acc1 += ob.x * w0 + ob.y * w1 + ob.z * w2 + ob.w * w3;
    }
    v[(size_t)(b0 + bp * 2) * (H * VH) + h * VH + vi] = acc0;
    v[(size_t)(b0 + bp * 2 + 1) * (H * VH) + h * VH + vi] = acc1;
}

// ---------------- Kernel 6: out_part[ks] = V[:, k-slice] @ W_O[k-slice, :]
__global__ void k_out(const float* __restrict__ v, const float* __restrict__ W_O,
                      float* __restrict__ out_part) {
    const int dsl = blockIdx.x, ksl = blockIdx.y, t = threadIdx.x;
    const int d0 = dsl * 128, k0 = ksl * 128;
    __shared__ float vs[32][128];
    for (int i = t; i < 32 * 128; i += 256) {
        const int bi = i >> 7, kk = i & 127;
        vs[bi][kk] = v[(size_t)bi * DM + k0 + kk];
    }
    __syncthreads();
    const int dl = t & 127, bh = t >> 7;
    float acc[16];
#pragma unroll
    for (int i = 0; i < 16; i++) acc[i] = 0.f;
    for (int kk = 0; kk < 128; kk += 4) {
        const float w0 = W_O[(size_t)(k0 + kk + 0) * DM + d0 + dl];
        const float w1 = W_O[(size_t)(k0 + kk + 1) * DM + d0 + dl];
        const float w2 = W_O[(size_t)(k0 + kk + 2) * DM + d0 + dl];
        const float w3 = W_O[(size_t)(k0 + kk + 3) * DM + d0 + dl];
#pragma unroll
        for (int i = 0; i < 16; i++) {
            const float4 vv = *(const float4*)&vs[bh * 16 + i][kk];
            acc[i] += vv.x * w0 + vv.y * w1 + vv.z * w2 + vv.w * w3;
        }
    }
    float* op = out_part + (size_t)ksl * 32 * DM;
#pragma unroll
    for (int i = 0; i < 16; i++) op[(size_t)(bh * 16 + i) * DM + d0 + dl] = acc[i];
}

// ---------------- Kernel 7: reduce the 16 split-K partials
__global__ void k_out_reduce(const float* __restrict__ out_part, float* __restrict__ out) {
    const int idx = blockIdx.x * 256 + threadIdx.x;
    float4 acc = make_float4(0.f, 0.f, 0.f, 0.f);
    for (int ks = 0; ks < 16; ks++) {
        float4 p = *(const float4*)(out_part + (size_t)ks * (32 * DM) + (size_t)idx * 4);
        acc.x += p.x; acc.y += p.y; acc.z += p.z; acc.w += p.w;
    }
    *(float4*)(out + (size_t)idx * 4) = acc;
}

extern "C" void kernel_launch(void* const* d_in, const int* in_sizes, int n_in,
                              void* d_out, int out_size, void* d_ws, size_t ws_size,
                              hipStream_t stream) {
    const float* q_c        = (const float*)d_in[0];
    const float* k_c_normed = (const float*)d_in[1];
    const float* k_pe       = (const float*)d_in[2];
    const float* kv_c_cache = (const float*)d_in[3];
    const float* k_pe_cache = (const float*)d_in[4];
    const float* W_UQ       = (const float*)d_in[5];
    const float* W_UK       = (const float*)d_in[6];
    const float* W_QR       = (const float*)d_in[7];
    const float* W_UV       = (const float*)d_in[8];
    const float* W_O        = (const float*)d_in[9];
    const int*   pos        = (const int*)d_in[10];

    float* ws = (float*)d_ws;
    float* q_t       = ws;                        // 65536 floats
    float* qbf_f     = q_t + 65536;               // 147456 floats reserved for q_bf
    ushort* q_bf     = (ushort*)qbf_f;            // [32][16][576] bf16
    float* kpe_rot   = qbf_f + 147456;            // 2048
    float* part_o    = kpe_rot + 2048;            // 8388608
    float* part_ml   = part_o + (size_t)B * NC * H * LORA;   // 32768
    float* v         = part_ml + (size_t)B * NC * H * 2;     // 65536
    float* out_part  = v + 65536;                 // 1048576
    float* proj_part = out_part + (size_t)16 * 32 * DM;      // 2359296

    k_proj_part<<<dim3(NKS, 12), 256, 0, stream>>>(q_c, W_UQ, W_QR, proj_part);
    k_finalize<<<81, 256, 0, stream>>>(proj_part, k_pe, pos, q_t, q_bf, kpe_rot);
    k_qnope<<<dim3(8, 16), 256, 0, stream>>>(q_t, W_UK, q_bf);
    k_flash<<<B * NC, 256, 0, stream>>>(q_bf, kv_c_cache, k_pe_cache,
                                        k_c_normed, kpe_rot, pos, part_o, part_ml);
    k_combine<<<dim3(8, 16), 256, 0, stream>>>(part_o, part_ml, W_UV, v);
    k_out<<<dim3(16, 16), 256, 0, stream>>>(v, W_O, out_part);
    k_out_reduce<<<64, 256, 0, stream>>>(out_part, (float*)d_out);
}

// Round 14
// 216.956 us; speedup vs baseline: 1.2064x; 1.0437x over previous
//
#include <hip/hip_runtime.h>
#include <hip/hip_bf16.h>
#include <math.h>

#define B 32
#define S 4096
#define H 16
#define QC 1536
#define LORA 512
#define ROPE 64
#define NOPE 128
#define VH 128
#define DM 2048
#define NC 32          // chunks per batch for flash split-K
#define CHUNK (S / NC) // 128 rows per chunk
#define NKS 24         // k-slices for proj1 split-K (1536/64)
#define FLP 584        // flash LDS row pitch in bf16 (b128-aligned, 2-way-free banks)

__device__ __constant__ float SCALE_C = 0.07216878364870323f; // 1/sqrt(192)

typedef __attribute__((ext_vector_type(8))) short bf16x8;
typedef __attribute__((ext_vector_type(4))) float f32x4;

__device__ inline ushort f2b(float x) { // fp32 -> bf16 RNE
    union { float f; uint u; } v; v.f = x;
    return (ushort)((v.u + 0x7FFFu + ((v.u >> 16) & 1u)) >> 16);
}

// ---------------- Kernel 1a: proj partials. grid (NKS=24, 12 col-slices), 256 thr.
__global__ __launch_bounds__(256) void k_proj_part(
    const float* __restrict__ q_c, const float* __restrict__ W_UQ,
    const float* __restrict__ W_QR, float* __restrict__ part) {
    const int ks = blockIdx.x, cs = blockIdx.y, t = threadIdx.x;
    const int k0 = ks * 64;
    __shared__ float qs[64][32]; // [k][b]
    for (int i = t; i < 64 * 32; i += 256) {
        const int k = i >> 5, b2 = i & 31;
        qs[k][b2] = q_c[(size_t)b2 * QC + k0 + k];
    }
    __syncthreads();
    const int tc = t & 63, tb = t >> 6;
    const int col = cs * 256 + tc * 4;
    const float* W; int N, coll;
    if (cs < 8) { W = W_UQ; N = 2048; coll = col; }
    else        { W = W_QR; N = 1024; coll = col - 2048; }
    float4 acc[8];
#pragma unroll
    for (int i = 0; i < 8; i++) acc[i] = make_float4(0.f, 0.f, 0.f, 0.f);
#pragma unroll 4
    for (int k = 0; k < 64; ++k) {
        const float4 w4 = *(const float4*)(W + (size_t)(k0 + k) * N + coll);
        const float4 a1 = *(const float4*)&qs[k][tb * 8];
        const float4 a2 = *(const float4*)&qs[k][tb * 8 + 4];
        acc[0].x += a1.x * w4.x; acc[0].y += a1.x * w4.y; acc[0].z += a1.x * w4.z; acc[0].w += a1.x * w4.w;
        acc[1].x += a1.y * w4.x; acc[1].y += a1.y * w4.y; acc[1].z += a1.y * w4.z; acc[1].w += a1.y * w4.w;
        acc[2].x += a1.z * w4.x; acc[2].y += a1.z * w4.y; acc[2].z += a1.z * w4.z; acc[2].w += a1.z * w4.w;
        acc[3].x += a1.w * w4.x; acc[3].y += a1.w * w4.y; acc[3].z += a1.w * w4.z; acc[3].w += a1.w * w4.w;
        acc[4].x += a2.x * w4.x; acc[4].y += a2.x * w4.y; acc[4].z += a2.x * w4.z; acc[4].w += a2.x * w4.w;
        acc[5].x += a2.y * w4.x; acc[5].y += a2.y * w4.y; acc[5].z += a2.y * w4.z; acc[5].w += a2.y * w4.w;
        acc[6].x += a2.z * w4.x; acc[6].y += a2.z * w4.y; acc[6].z += a2.z * w4.z; acc[6].w += a2.z * w4.w;
        acc[7].x += a2.w * w4.x; acc[7].y += a2.w * w4.y; acc[7].z += a2.w * w4.z; acc[7].w += a2.w * w4.w;
    }
#pragma unroll
    for (int j = 0; j < 8; j++) {
        const int b2 = tb * 8 + j;
        *(float4*)(part + ((size_t)ks * 32 + b2) * 3072 + col) = acc[j];
    }
}

// ---------------- Kernel 1b: fused reduce(24 partials) + RoPE.
__global__ __launch_bounds__(256) void k_finalize(
    const float* __restrict__ part, const float* __restrict__ k_pe,
    const int* __restrict__ pos_arr, float* __restrict__ q_t,
    ushort* __restrict__ q_bf, float* __restrict__ kpe_rot) {
    const int blk = blockIdx.x, t = threadIdx.x;
    if (blk < 64) {
        const int idx = blk * 256 + t;
        const int b = idx >> 9, c4 = idx & 511;
        const int col = c4 * 4;
        float4 acc = make_float4(0.f, 0.f, 0.f, 0.f);
        for (int ks = 0; ks < NKS; ks++) {
            const float4 p = *(const float4*)(part + ((size_t)ks * 32 + b) * 3072 + col);
            acc.x += p.x; acc.y += p.y; acc.z += p.z; acc.w += p.w;
        }
        *(float4*)(q_t + (size_t)b * 2048 + col) = acc;
    } else if (blk < 80) {
        const int idx = (blk - 64) * 256 + t;
        const int b = idx >> 7, rest = idx & 127;
        const int h = rest >> 3, pr = rest & 7;
        const int col1 = 2048 + h * 64 + pr * 4;
        float x1[4] = {0.f, 0.f, 0.f, 0.f}, x2[4] = {0.f, 0.f, 0.f, 0.f};
        for (int ks = 0; ks < NKS; ks++) {
            const float* p = part + ((size_t)ks * 32 + b) * 3072;
            const float4 a = *(const float4*)(p + col1);
            const float4 c = *(const float4*)(p + col1 + 32);
            x1[0] += a.x; x1[1] += a.y; x1[2] += a.z; x1[3] += a.w;
            x2[0] += c.x; x2[1] += c.y; x2[2] += c.z; x2[3] += c.w;
        }
        const int pos = pos_arr[b];
        ushort* qb = q_bf + ((size_t)b * 16 + h) * 576 + 512 + pr * 4;
#pragma unroll
        for (int e = 0; e < 4; ++e) {
            const int j = pr * 4 + e;
            const double inv = pow(10000.0, -(double)j / 32.0);
            const double f = (double)pos * inv;
            const float cc = (float)cos(f), ss = (float)sin(f);
            qb[e] = f2b(x1[e] * cc - x2[e] * ss);
            qb[32 + e] = f2b(x2[e] * cc + x1[e] * ss);
        }
    } else {
        for (int i = t; i < 32 * 32; i += 256) {
            const int b = i >> 5, j = i & 31;
            const int pos = pos_arr[b];
            const double inv = pow(10000.0, -(double)j / 32.0);
            const double f = (double)pos * inv;
            const float cc = (float)cos(f), ss = (float)sin(f);
            const float x1 = k_pe[(size_t)b * 64 + j], x2 = k_pe[(size_t)b * 64 + j + 32];
            kpe_rot[(size_t)b * 64 + j] = x1 * cc - x2 * ss;
            kpe_rot[(size_t)b * 64 + j + 32] = x2 * cc + x1 * ss;
        }
    }
}

// ---------------- Kernel 3: q_bf[b,h,l] = bf16( sum_n q_t[b,h,n] * W_UK[l,h,n] )
__global__ __launch_bounds__(256) void k_qnope(
    const float* __restrict__ q_t, const float* __restrict__ W_UK,
    ushort* __restrict__ q_bf) {
    const int l0 = blockIdx.x * 64, h = blockIdx.y;
    const int t = threadIdx.x;
    __shared__ float qs[32][NOPE]; // 16 KB
    for (int i = t; i < 32 * NOPE; i += 256) {
        const int b2 = i >> 7, n = i & 127;
        qs[b2][n] = q_t[(size_t)b2 * 2048 + h * NOPE + n];
    }
    __syncthreads();
    const int wave = t >> 6, lane = t & 63;
    const int half = lane >> 5, nl = (lane & 31) * 4;
    for (int sw = 0; sw < 8; ++sw) {
        const int l = l0 + sw * 8 + wave * 2 + half;
        const float4 w4 = *(const float4*)(W_UK + ((size_t)l * H + h) * NOPE + nl);
        for (int b2 = 0; b2 < 32; ++b2) {
            const float4 a4 = *(const float4*)&qs[b2][nl];
            float d = a4.x * w4.x + a4.y * w4.y + a4.z * w4.z + a4.w * w4.w;
            d += __shfl_xor(d, 16);
            d += __shfl_xor(d, 8);
            d += __shfl_xor(d, 4);
            d += __shfl_xor(d, 2);
            d += __shfl_xor(d, 1);
            if ((lane & 31) == 0)
                q_bf[((size_t)b2 * 16 + h) * 576 + l] = f2b(d);
        }
    }
}

// ---------------- Kernel 4: MFMA flash decode (bf16), 3-buffer / 1-barrier-per-tile
// Block = 256 thr = 4 waves; one (b, 128-row chunk) per block.
// 16-row K-tiles: global->reg (2-deep prefetch, two named reg sets) ->bf16->LDS
// rotating over 3 buffers; ONE barrier per tile. Tile t lives in buf[t%3];
// write of tile t+1 at tile t is safe (last readers of that buffer were tile
// t-2, separated by two barriers). PV at odd t reads buffers (t-1+half)%3.
__global__ __launch_bounds__(256) void k_flash(
    const ushort* __restrict__ q_bf, const float* __restrict__ kv_cache,
    const float* __restrict__ kpe_cache, const float* __restrict__ k_c_normed,
    const float* __restrict__ kpe_rot, const int* __restrict__ pos_arr,
    float* __restrict__ part_o, float* __restrict__ part_ml) {
    __shared__ ushort k_lds[3][16][FLP]; // 56 KB
    __shared__ uint p_lds[4][16][20];    //  5 KB (wave-private P bounce)
    const int blk = blockIdx.x;
    const int b = blk / NC, c = blk % NC;
    const int t = threadIdx.x, lane = t & 63, wave = t >> 6;
    const int lg = lane >> 4, hd = lane & 15;
    const int pos = pos_arr[b];
    const int s0 = c * CHUNK;
    const int rel = pos - s0;
    const int pt = (rel >= 0 && rel < CHUNK) ? (rel >> 4) : -1;
    const int prow = rel & 15;

    const float* kv_b = kv_cache + (size_t)b * S * LORA;
    const float* kp_b = kpe_cache + (size_t)b * S * ROPE;
    const float* kc_b = k_c_normed + (size_t)b * LORA;
    const float* kr_b = kpe_rot + (size_t)b * ROPE;

    // Q fragments: head hd, dims 32*ks + lg*8 + i  (B-operand layout)
    bf16x8 qf[18];
    {
        const ushort* qr = q_bf + ((size_t)b * 16 + hd) * 576 + lg * 8;
#pragma unroll
        for (int ks = 0; ks < 18; ++ks)
            qf[ks] = *(const bf16x8*)(qr + 32 * ks);
    }

    float4 ldA[9], ldB[9];
    auto issue = [&](int tile, float4 (&ld)[9]) { // global loads -> regs
        const int r = t >> 4, f0 = t & 15;
        const int s = s0 + tile * 16 + r;
        const float* kvr = kv_b + (size_t)s * LORA;
        const float* per = kp_b + (size_t)s * ROPE;
#pragma unroll
        for (int k = 0; k < 8; ++k) ld[k] = *(const float4*)(kvr + 4 * (f0 + 16 * k));
        ld[8] = *(const float4*)(per + 4 * f0);
    };
    auto wtile = [&](float4 (&ld)[9], int buf) { // bf16-convert + LDS write
        const int r = t >> 4, f0 = t & 15;
        ushort* dst = &k_lds[buf][r][0];
#pragma unroll
        for (int k = 0; k < 9; ++k) {
            const int f = f0 + 16 * k;
            ushort4 h4;
            h4.x = f2b(ld[k].x); h4.y = f2b(ld[k].y);
            h4.z = f2b(ld[k].z); h4.w = f2b(ld[k].w);
            *(ushort4*)(dst + 4 * f) = h4;
        }
    };
    auto patch = [&](int buf) { // replace pos-row with k_c_normed / kpe_rot
        if (t < 144) {
            const float4 v = (t < 128) ? *(const float4*)(kc_b + 4 * t)
                                       : *(const float4*)(kr_b + 4 * (t - 128));
            ushort4 h4;
            h4.x = f2b(v.x); h4.y = f2b(v.y); h4.z = f2b(v.z); h4.w = f2b(v.w);
            *(ushort4*)(&k_lds[buf][prow][4 * t]) = h4;
        }
    };

    f32x4 acc[8];
#pragma unroll
    for (int i = 0; i < 8; ++i) acc[i] = (f32x4){0.f, 0.f, 0.f, 0.f};
    float m_run = -INFINITY, l_run = 0.f;

    // one tile's worth of work: QK -> online softmax -> (odd t) PV
    auto compute = [&](int tt) {
        // ---- QK^T for this 16-row tile
        f32x4 S4 = (f32x4){0.f, 0.f, 0.f, 0.f};
        {
            const ushort* krow = &k_lds[tt % 3][hd][lg * 8];
#pragma unroll
            for (int ks = 0; ks < 18; ++ks) {
                const bf16x8 av = *(const bf16x8*)(krow + 32 * ks);
                S4 = __builtin_amdgcn_mfma_f32_16x16x32_bf16(av, qf[ks], S4, 0, 0, 0);
            }
        }
        const float sc0 = S4[0] * SCALE_C, sc1 = S4[1] * SCALE_C;
        const float sc2 = S4[2] * SCALE_C, sc3 = S4[3] * SCALE_C;

        // ---- online softmax (per-head state lives in lanes with hd == head)
        float smax = fmaxf(fmaxf(sc0, sc1), fmaxf(sc2, sc3));
        smax = fmaxf(smax, __shfl_xor(smax, 16));
        smax = fmaxf(smax, __shfl_xor(smax, 32));
        const bool need = smax > m_run + 8.0f;
        if (__any(need)) {
            const float m_new = need ? smax : m_run;
            const float alpha = __expf(m_run - m_new);
            l_run *= alpha;
            m_run = m_new;
            const int hb = lg * 4;
            const float a0 = __shfl(alpha, hb + 0), a1 = __shfl(alpha, hb + 1);
            const float a2 = __shfl(alpha, hb + 2), a3 = __shfl(alpha, hb + 3);
#pragma unroll
            for (int d2 = 0; d2 < 8; ++d2) {
                acc[d2][0] *= a0; acc[d2][1] *= a1;
                acc[d2][2] *= a2; acc[d2][3] *= a3;
            }
        }
        const float p0 = __expf(sc0 - m_run), p1 = __expf(sc1 - m_run);
        const float p2 = __expf(sc2 - m_run), p3 = __expf(sc3 - m_run);
        float ps = p0 + p1 + p2 + p3;
        ps += __shfl_xor(ps, 16);
        ps += __shfl_xor(ps, 32);
        l_run += ps;
        const uint plo = (uint)f2b(p0) | ((uint)f2b(p1) << 16);
        const uint phi = (uint)f2b(p2) | ((uint)f2b(p3) << 16);
        *(uint2*)&p_lds[wave][hd][(tt & 1) * 8 + lg * 2] = make_uint2(plo, phi);

        // ---- PV over the 32 rows of tiles {tt-1, tt}
        if (tt & 1) {
            const bf16x8 ap = *(const bf16x8*)&p_lds[wave][hd][lg * 4];
            const int half = lane >> 5;                 // 0 -> tile tt-1, 1 -> tile tt
            const int bsel = (tt - 1 + half) % 3;
            const int rbase = (lg & 1) * 8;
#pragma unroll
            for (int dt = 0; dt < 8; ++dt) {
                const int dcol = wave * 128 + dt * 16 + hd;
                union { bf16x8 v; ushort u[8]; } bv;
#pragma unroll
                for (int i2 = 0; i2 < 8; ++i2)
                    bv.u[i2] = k_lds[bsel][rbase + i2][dcol];
                acc[dt] = __builtin_amdgcn_mfma_f32_16x16x32_bf16(ap, bv.v, acc[dt], 0, 0, 0);
            }
        }
    };

    // prologue: tile0 -> buf0 (immediate), tile1 issued into ldA
    issue(0, ldB);
    wtile(ldB, 0);
    if (pt == 0) patch(0);
    issue(1, ldA);
    __syncthreads();

    // main loop: 2 tiles per iteration, ONE barrier per tile.
    for (int tb = 0; tb < 8; tb += 2) {
        // even tile tb: regs ldA hold tile tb+1
        if (tb + 2 < 8) issue(tb + 2, ldB);
        compute(tb);
        wtile(ldA, (tb + 1) % 3);                 // tb+1 <= 7 always
        if (pt == tb + 1) patch((tb + 1) % 3);
        __syncthreads();
        // odd tile tb+1: regs ldB hold tile tb+2 (if any)
        if (tb + 3 < 8) issue(tb + 3, ldA);
        compute(tb + 1);
        if (tb + 2 < 8) {
            wtile(ldB, (tb + 2) % 3);
            if (pt == tb + 2) patch((tb + 2) % 3);
        }
        __syncthreads();
    }

    // ---- epilogue: O[head = lg*4+reg][dim = wave*128 + dt*16 + hd]
    float* po = part_o + ((size_t)(b * NC + c) * H) * LORA;
#pragma unroll
    for (int dt = 0; dt < 8; ++dt) {
        const int dim = wave * 128 + dt * 16 + hd;
        const int hb = lg * 4;
        po[(size_t)(hb + 0) * LORA + dim] = acc[dt][0];
        po[(size_t)(hb + 1) * LORA + dim] = acc[dt][1];
        po[(size_t)(hb + 2) * LORA + dim] = acc[dt][2];
        po[(size_t)(hb + 3) * LORA + dim] = acc[dt][3];
    }
    if (wave == 0 && lane < 16) {
        float* pml = part_ml + ((size_t)(b * NC + c) * H + lane) * 2;
        pml[0] = m_run;
        pml[1] = l_run;
    }
}

// ---------------- Kernel 5: combine partials -> o (LDS), fused v = o . W_UV
__global__ __launch_bounds__(256) void k_combine(
    const float* __restrict__ part_o, const float* __restrict__ part_ml,
    const float* __restrict__ W_UV, float* __restrict__ v) {
    const int b0 = blockIdx.x * 4, h = blockIdx.y, t = threadIdx.x;
    __shared__ float ml_s[4][NC][2];
    __shared__ float o_s[4][LORA]; // 8 KB
    if (t < 256) {
        const int b2 = t >> 6, c = (t >> 1) & 31, w = t & 1;
        ml_s[b2][c][w] = part_ml[(((size_t)(b0 + b2) * NC + c) * H + h) * 2 + w];
    }
    __syncthreads();
    float m_b[4], inv_l[4];
#pragma unroll
    for (int b2 = 0; b2 < 4; ++b2) {
        float m = -INFINITY;
        for (int c = 0; c < NC; c++) m = fmaxf(m, ml_s[b2][c][0]);
        float l = 0.f;
        for (int c = 0; c < NC; c++) l += ml_s[b2][c][1] * __expf(ml_s[b2][c][0] - m);
        m_b[b2] = m;
        inv_l[b2] = 1.0f / l;
    }
    for (int i = t; i < 4 * LORA; i += 256) {
        const int b2 = i >> 9, li = i & 511;
        float acc = 0.f;
        for (int c = 0; c < NC; c++) {
            acc += part_o[(((size_t)(b0 + b2) * NC + c) * H + h) * LORA + li] *
                   __expf(ml_s[b2][c][0] - m_b[b2]);
        }
        o_s[b2][li] = acc * inv_l[b2];
    }
    __syncthreads();
    const int vi = t & 127, bp = t >> 7;
    float acc0 = 0.f, acc1 = 0.f;
    for (int l = 0; l < LORA; l += 4) {
        const float w0 = W_UV[(size_t)(l + 0) * (H * VH) + h * VH + vi];
        const float w1 = W_UV[(size_t)(l + 1) * (H * VH) + h * VH + vi];
        const float w2 = W_UV[(size_t)(l + 2) * (H * VH) + h * VH + vi];
        const float w3 = W_UV[(size_t)(l + 3) * (H * VH) + h * VH + vi];
        const float4 oa = *(const float4*)&o_s[bp * 2][l];
        const float4 ob = *(const float4*)&o_s[bp * 2 + 1][l];
        acc0 += oa.x * w0 + oa.y * w1 + oa.z * w2 + oa.w * w3;
        acc1 += ob.x * w0 + ob.y * w1 + ob.z * w2 + ob.w * w3;
    }
    v[(size_t)(b0 + bp * 2) * (H * VH) + h * VH + vi] = acc0;
    v[(size_t)(b0 + bp * 2 + 1) * (H * VH) + h * VH + vi] = acc1;
}

// ---------------- Kernel 6: out_part[ks] = V[:, k-slice] @ W_O[k-slice, :]
__global__ void k_out(const float* __restrict__ v, const float* __restrict__ W_O,
                      float* __restrict__ out_part) {
    const int dsl = blockIdx.x, ksl = blockIdx.y, t = threadIdx.x;
    const int d0 = dsl * 128, k0 = ksl * 128;
    __shared__ float vs[32][128];
    for (int i = t; i < 32 * 128; i += 256) {
        const int bi = i >> 7, kk = i & 127;
        vs[bi][kk] = v[(size_t)bi * DM + k0 + kk];
    }
    __syncthreads();
    const int dl = t & 127, bh = t >> 7;
    float acc[16];
#pragma unroll
    for (int i = 0; i < 16; i++) acc[i] = 0.f;
    for (int kk = 0; kk < 128; kk += 4) {
        const float w0 = W_O[(size_t)(k0 + kk + 0) * DM + d0 + dl];
        const float w1 = W_O[(size_t)(k0 + kk + 1) * DM + d0 + dl];
        const float w2 = W_O[(size_t)(k0 + kk + 2) * DM + d0 + dl];
        const float w3 = W_O[(size_t)(k0 + kk + 3) * DM + d0 + dl];
#pragma unroll
        for (int i = 0; i < 16; i++) {
            const float4 vv = *(const float4*)&vs[bh * 16 + i][kk];
            acc[i] += vv.x * w0 + vv.y * w1 + vv.z * w2 + vv.w * w3;
        }
    }
    float* op = out_part + (size_t)ksl * 32 * DM;
#pragma unroll
    for (int i = 0; i < 16; i++) op[(size_t)(bh * 16 + i) * DM + d0 + dl] = acc[i];
}

// ---------------- Kernel 7: reduce the 16 split-K partials
__global__ void k_out_reduce(const float* __restrict__ out_part, float* __restrict__ out) {
    const int idx = blockIdx.x * 256 + threadIdx.x;
    float4 acc = make_float4(0.f, 0.f, 0.f, 0.f);
    for (int ks = 0; ks < 16; ks++) {
        float4 p = *(const float4*)(out_part + (size_t)ks * (32 * DM) + (size_t)idx * 4);
        acc.x += p.x; acc.y += p.y; acc.z += p.z; acc.w += p.w;
    }
    *(float4*)(out + (size_t)idx * 4) = acc;
}

extern "C" void kernel_launch(void* const* d_in, const int* in_sizes, int n_in,
                              void* d_out, int out_size, void* d_ws, size_t ws_size,
                              hipStream_t stream) {
    const float* q_c        = (const float*)d_in[0];
    const float* k_c_normed = (const float*)d_in[1];
    const float* k_pe       = (const float*)d_in[2];
    const float* kv_c_cache = (const float*)d_in[3];
    const float* k_pe_cache = (const float*)d_in[4];
    const float* W_UQ       = (const float*)d_in[5];
    const float* W_UK       = (const float*)d_in[6];
    const float* W_QR       = (const float*)d_in[7];
    const float* W_UV       = (const float*)d_in[8];
    const float* W_O        = (const float*)d_in[9];
    const int*   pos        = (const int*)d_in[10];

    float* ws = (float*)d_ws;
    float* q_t       = ws;                        // 65536 floats
    float* qbf_f     = q_t + 65536;               // 147456 floats reserved for q_bf
    ushort* q_bf     = (ushort*)qbf_f;            // [32][16][576] bf16
    float* kpe_rot   = qbf_f + 147456;            // 2048
    float* part_o    = kpe_rot + 2048;            // 8388608
    float* part_ml   = part_o + (size_t)B * NC * H * LORA;   // 32768
    float* v         = part_ml + (size_t)B * NC * H * 2;     // 65536
    float* out_part  = v + 65536;                 // 1048576
    float* proj_part = out_part + (size_t)16 * 32 * DM;      // 2359296

    k_proj_part<<<dim3(NKS, 12), 256, 0, stream>>>(q_c, W_UQ, W_QR, proj_part);
    k_finalize<<<81, 256, 0, stream>>>(proj_part, k_pe, pos, q_t, q_bf, kpe_rot);
    k_qnope<<<dim3(8, 16), 256, 0, stream>>>(q_t, W_UK, q_bf);
    k_flash<<<B * NC, 256, 0, stream>>>(q_bf, kv_c_cache, k_pe_cache,
                                        k_c_normed, kpe_rot, pos, part_o, part_ml);
    k_combine<<<dim3(8, 16), 256, 0, stream>>>(part_o, part_ml, W_UV, v);
    k_out<<<dim3(16, 16), 256, 0, stream>>>(v, W_O, out_part);
    k_out_reduce<<<64, 256, 0, stream>>>(out_part, (float*)d_out);
}

// Round 15
// 208.022 us; speedup vs baseline: 1.2583x; 1.0429x over previous
//
#include <hip/hip_runtime.h>
#include <hip/hip_bf16.h>
#include <math.h>

#define B 32
#define S 4096
#define H 16
#define QC 1536
#define LORA 512
#define ROPE 64
#define NOPE 128
#define VH 128
#define DM 2048
#define NC 16          // chunks per batch for flash split-K
#define CHUNK (S / NC) // 256 rows per chunk
#define NTIL (CHUNK / 16) // 16-row tiles per chunk
#define NKS 24         // k-slices for proj1 split-K (1536/64)
#define FLP 584        // flash LDS row pitch in bf16 (b128-aligned, 2-way-free banks)

__device__ __constant__ float SCALE_C = 0.07216878364870323f; // 1/sqrt(192)

typedef __attribute__((ext_vector_type(8))) short bf16x8;
typedef __attribute__((ext_vector_type(4))) float f32x4;

__device__ inline ushort f2b(float x) { // fp32 -> bf16 RNE
    union { float f; uint u; } v; v.f = x;
    return (ushort)((v.u + 0x7FFFu + ((v.u >> 16) & 1u)) >> 16);
}

// ---------------- Kernel 1a: proj partials. grid (NKS=24, 12 col-slices), 256 thr.
__global__ __launch_bounds__(256) void k_proj_part(
    const float* __restrict__ q_c, const float* __restrict__ W_UQ,
    const float* __restrict__ W_QR, float* __restrict__ part) {
    const int ks = blockIdx.x, cs = blockIdx.y, t = threadIdx.x;
    const int k0 = ks * 64;
    __shared__ float qs[64][32]; // [k][b]
    for (int i = t; i < 64 * 32; i += 256) {
        const int k = i >> 5, b2 = i & 31;
        qs[k][b2] = q_c[(size_t)b2 * QC + k0 + k];
    }
    __syncthreads();
    const int tc = t & 63, tb = t >> 6;
    const int col = cs * 256 + tc * 4;
    const float* W; int N, coll;
    if (cs < 8) { W = W_UQ; N = 2048; coll = col; }
    else        { W = W_QR; N = 1024; coll = col - 2048; }
    float4 acc[8];
#pragma unroll
    for (int i = 0; i < 8; i++) acc[i] = make_float4(0.f, 0.f, 0.f, 0.f);
#pragma unroll 4
    for (int k = 0; k < 64; ++k) {
        const float4 w4 = *(const float4*)(W + (size_t)(k0 + k) * N + coll);
        const float4 a1 = *(const float4*)&qs[k][tb * 8];
        const float4 a2 = *(const float4*)&qs[k][tb * 8 + 4];
        acc[0].x += a1.x * w4.x; acc[0].y += a1.x * w4.y; acc[0].z += a1.x * w4.z; acc[0].w += a1.x * w4.w;
        acc[1].x += a1.y * w4.x; acc[1].y += a1.y * w4.y; acc[1].z += a1.y * w4.z; acc[1].w += a1.y * w4.w;
        acc[2].x += a1.z * w4.x; acc[2].y += a1.z * w4.y; acc[2].z += a1.z * w4.z; acc[2].w += a1.z * w4.w;
        acc[3].x += a1.w * w4.x; acc[3].y += a1.w * w4.y; acc[3].z += a1.w * w4.z; acc[3].w += a1.w * w4.w;
        acc[4].x += a2.x * w4.x; acc[4].y += a2.x * w4.y; acc[4].z += a2.x * w4.z; acc[4].w += a2.x * w4.w;
        acc[5].x += a2.y * w4.x; acc[5].y += a2.y * w4.y; acc[5].z += a2.y * w4.z; acc[5].w += a2.y * w4.w;
        acc[6].x += a2.z * w4.x; acc[6].y += a2.z * w4.y; acc[6].z += a2.z * w4.z; acc[6].w += a2.z * w4.w;
        acc[7].x += a2.w * w4.x; acc[7].y += a2.w * w4.y; acc[7].z += a2.w * w4.z; acc[7].w += a2.w * w4.w;
    }
#pragma unroll
    for (int j = 0; j < 8; j++) {
        const int b2 = tb * 8 + j;
        *(float4*)(part + ((size_t)ks * 32 + b2) * 3072 + col) = acc[j];
    }
}

// ---------------- Kernel 1b: fused reduce(24 partials) + RoPE.
__global__ __launch_bounds__(256) void k_finalize(
    const float* __restrict__ part, const float* __restrict__ k_pe,
    const int* __restrict__ pos_arr, float* __restrict__ q_t,
    ushort* __restrict__ q_bf, float* __restrict__ kpe_rot) {
    const int blk = blockIdx.x, t = threadIdx.x;
    if (blk < 64) {
        const int idx = blk * 256 + t;
        const int b = idx >> 9, c4 = idx & 511;
        const int col = c4 * 4;
        float4 acc = make_float4(0.f, 0.f, 0.f, 0.f);
        for (int ks = 0; ks < NKS; ks++) {
            const float4 p = *(const float4*)(part + ((size_t)ks * 32 + b) * 3072 + col);
            acc.x += p.x; acc.y += p.y; acc.z += p.z; acc.w += p.w;
        }
        *(float4*)(q_t + (size_t)b * 2048 + col) = acc;
    } else if (blk < 80) {
        const int idx = (blk - 64) * 256 + t;
        const int b = idx >> 7, rest = idx & 127;
        const int h = rest >> 3, pr = rest & 7;
        const int col1 = 2048 + h * 64 + pr * 4;
        float x1[4] = {0.f, 0.f, 0.f, 0.f}, x2[4] = {0.f, 0.f, 0.f, 0.f};
        for (int ks = 0; ks < NKS; ks++) {
            const float* p = part + ((size_t)ks * 32 + b) * 3072;
            const float4 a = *(const float4*)(p + col1);
            const float4 c = *(const float4*)(p + col1 + 32);
            x1[0] += a.x; x1[1] += a.y; x1[2] += a.z; x1[3] += a.w;
            x2[0] += c.x; x2[1] += c.y; x2[2] += c.z; x2[3] += c.w;
        }
        const int pos = pos_arr[b];
        ushort* qb = q_bf + ((size_t)b * 16 + h) * 576 + 512 + pr * 4;
#pragma unroll
        for (int e = 0; e < 4; ++e) {
            const int j = pr * 4 + e;
            const double inv = pow(10000.0, -(double)j / 32.0);
            const double f = (double)pos * inv;
            const float cc = (float)cos(f), ss = (float)sin(f);
            qb[e] = f2b(x1[e] * cc - x2[e] * ss);
            qb[32 + e] = f2b(x2[e] * cc + x1[e] * ss);
        }
    } else {
        for (int i = t; i < 32 * 32; i += 256) {
            const int b = i >> 5, j = i & 31;
            const int pos = pos_arr[b];
            const double inv = pow(10000.0, -(double)j / 32.0);
            const double f = (double)pos * inv;
            const float cc = (float)cos(f), ss = (float)sin(f);
            const float x1 = k_pe[(size_t)b * 64 + j], x2 = k_pe[(size_t)b * 64 + j + 32];
            kpe_rot[(size_t)b * 64 + j] = x1 * cc - x2 * ss;
            kpe_rot[(size_t)b * 64 + j + 32] = x2 * cc + x1 * ss;
        }
    }
}

// ---------------- Kernel 3: q_bf[b,h,l] = bf16( sum_n q_t[b,h,n] * W_UK[l,h,n] )
__global__ __launch_bounds__(256) void k_qnope(
    const float* __restrict__ q_t, const float* __restrict__ W_UK,
    ushort* __restrict__ q_bf) {
    const int l0 = blockIdx.x * 64, h = blockIdx.y;
    const int t = threadIdx.x;
    __shared__ float qs[32][NOPE]; // 16 KB
    for (int i = t; i < 32 * NOPE; i += 256) {
        const int b2 = i >> 7, n = i & 127;
        qs[b2][n] = q_t[(size_t)b2 * 2048 + h * NOPE + n];
    }
    __syncthreads();
    const int wave = t >> 6, lane = t & 63;
    const int half = lane >> 5, nl = (lane & 31) * 4;
    for (int sw = 0; sw < 8; ++sw) {
        const int l = l0 + sw * 8 + wave * 2 + half;
        const float4 w4 = *(const float4*)(W_UK + ((size_t)l * H + h) * NOPE + nl);
        for (int b2 = 0; b2 < 32; ++b2) {
            const float4 a4 = *(const float4*)&qs[b2][nl];
            float d = a4.x * w4.x + a4.y * w4.y + a4.z * w4.z + a4.w * w4.w;
            d += __shfl_xor(d, 16);
            d += __shfl_xor(d, 8);
            d += __shfl_xor(d, 4);
            d += __shfl_xor(d, 2);
            d += __shfl_xor(d, 1);
            if ((lane & 31) == 0)
                q_bf[((size_t)b2 * 16 + h) * 576 + l] = f2b(d);
        }
    }
}

// ---------------- Kernel 4: MFMA flash decode (bf16), 3-buffer / 1-barrier-per-tile
// Block = 256 thr = 4 waves; one (b, 256-row chunk) per block, 16 tiles.
// 16-row K-tiles: global->reg (2-deep prefetch, two named reg sets) ->bf16->LDS
// rotating over 3 buffers; ONE barrier per tile.
__global__ __launch_bounds__(256) void k_flash(
    const ushort* __restrict__ q_bf, const float* __restrict__ kv_cache,
    const float* __restrict__ kpe_cache, const float* __restrict__ k_c_normed,
    const float* __restrict__ kpe_rot, const int* __restrict__ pos_arr,
    float* __restrict__ part_o, float* __restrict__ part_ml) {
    __shared__ ushort k_lds[3][16][FLP]; // 56 KB
    __shared__ uint p_lds[4][16][20];    //  5 KB (wave-private P bounce)
    const int blk = blockIdx.x;
    const int b = blk / NC, c = blk % NC;
    const int t = threadIdx.x, lane = t & 63, wave = t >> 6;
    const int lg = lane >> 4, hd = lane & 15;
    const int pos = pos_arr[b];
    const int s0 = c * CHUNK;
    const int rel = pos - s0;
    const int pt = (rel >= 0 && rel < CHUNK) ? (rel >> 4) : -1;
    const int prow = rel & 15;

    const float* kv_b = kv_cache + (size_t)b * S * LORA;
    const float* kp_b = kpe_cache + (size_t)b * S * ROPE;
    const float* kc_b = k_c_normed + (size_t)b * LORA;
    const float* kr_b = kpe_rot + (size_t)b * ROPE;

    // Q fragments: head hd, dims 32*ks + lg*8 + i  (B-operand layout)
    bf16x8 qf[18];
    {
        const ushort* qr = q_bf + ((size_t)b * 16 + hd) * 576 + lg * 8;
#pragma unroll
        for (int ks = 0; ks < 18; ++ks)
            qf[ks] = *(const bf16x8*)(qr + 32 * ks);
    }

    float4 ldA[9], ldB[9];
    auto issue = [&](int tile, float4 (&ld)[9]) { // global loads -> regs
        const int r = t >> 4, f0 = t & 15;
        const int s = s0 + tile * 16 + r;
        const float* kvr = kv_b + (size_t)s * LORA;
        const float* per = kp_b + (size_t)s * ROPE;
#pragma unroll
        for (int k = 0; k < 8; ++k) ld[k] = *(const float4*)(kvr + 4 * (f0 + 16 * k));
        ld[8] = *(const float4*)(per + 4 * f0);
    };
    auto wtile = [&](float4 (&ld)[9], int buf) { // bf16-convert + LDS write
        const int r = t >> 4, f0 = t & 15;
        ushort* dst = &k_lds[buf][r][0];
#pragma unroll
        for (int k = 0; k < 9; ++k) {
            const int f = f0 + 16 * k;
            ushort4 h4;
            h4.x = f2b(ld[k].x); h4.y = f2b(ld[k].y);
            h4.z = f2b(ld[k].z); h4.w = f2b(ld[k].w);
            *(ushort4*)(dst + 4 * f) = h4;
        }
    };
    auto patch = [&](int buf) { // replace pos-row with k_c_normed / kpe_rot
        if (t < 144) {
            const float4 v = (t < 128) ? *(const float4*)(kc_b + 4 * t)
                                       : *(const float4*)(kr_b + 4 * (t - 128));
            ushort4 h4;
            h4.x = f2b(v.x); h4.y = f2b(v.y); h4.z = f2b(v.z); h4.w = f2b(v.w);
            *(ushort4*)(&k_lds[buf][prow][4 * t]) = h4;
        }
    };

    f32x4 acc[8];
#pragma unroll
    for (int i = 0; i < 8; ++i) acc[i] = (f32x4){0.f, 0.f, 0.f, 0.f};
    float m_run = -INFINITY, l_run = 0.f;

    // one tile's worth of work: QK -> online softmax -> (odd t) PV
    auto compute = [&](int tt) {
        // ---- QK^T for this 16-row tile
        f32x4 S4 = (f32x4){0.f, 0.f, 0.f, 0.f};
        {
            const ushort* krow = &k_lds[tt % 3][hd][lg * 8];
#pragma unroll
            for (int ks = 0; ks < 18; ++ks) {
                const bf16x8 av = *(const bf16x8*)(krow + 32 * ks);
                S4 = __builtin_amdgcn_mfma_f32_16x16x32_bf16(av, qf[ks], S4, 0, 0, 0);
            }
        }
        const float sc0 = S4[0] * SCALE_C, sc1 = S4[1] * SCALE_C;
        const float sc2 = S4[2] * SCALE_C, sc3 = S4[3] * SCALE_C;

        // ---- online softmax (per-head state lives in lanes with hd == head)
        float smax = fmaxf(fmaxf(sc0, sc1), fmaxf(sc2, sc3));
        smax = fmaxf(smax, __shfl_xor(smax, 16));
        smax = fmaxf(smax, __shfl_xor(smax, 32));
        const bool need = smax > m_run + 8.0f;
        if (__any(need)) {
            const float m_new = need ? smax : m_run;
            const float alpha = __expf(m_run - m_new);
            l_run *= alpha;
            m_run = m_new;
            const int hb = lg * 4;
            const float a0 = __shfl(alpha, hb + 0), a1 = __shfl(alpha, hb + 1);
            const float a2 = __shfl(alpha, hb + 2), a3 = __shfl(alpha, hb + 3);
#pragma unroll
            for (int d2 = 0; d2 < 8; ++d2) {
                acc[d2][0] *= a0; acc[d2][1] *= a1;
                acc[d2][2] *= a2; acc[d2][3] *= a3;
            }
        }
        const float p0 = __expf(sc0 - m_run), p1 = __expf(sc1 - m_run);
        const float p2 = __expf(sc2 - m_run), p3 = __expf(sc3 - m_run);
        float ps = p0 + p1 + p2 + p3;
        ps += __shfl_xor(ps, 16);
        ps += __shfl_xor(ps, 32);
        l_run += ps;
        const uint plo = (uint)f2b(p0) | ((uint)f2b(p1) << 16);
        const uint phi = (uint)f2b(p2) | ((uint)f2b(p3) << 16);
        *(uint2*)&p_lds[wave][hd][(tt & 1) * 8 + lg * 2] = make_uint2(plo, phi);

        // ---- PV over the 32 rows of tiles {tt-1, tt}
        if (tt & 1) {
            const bf16x8 ap = *(const bf16x8*)&p_lds[wave][hd][lg * 4];
            const int half = lane >> 5;                 // 0 -> tile tt-1, 1 -> tile tt
            const int bsel = (tt - 1 + half) % 3;
            const int rbase = (lg & 1) * 8;
#pragma unroll
            for (int dt = 0; dt < 8; ++dt) {
                const int dcol = wave * 128 + dt * 16 + hd;
                union { bf16x8 v; ushort u[8]; } bv;
#pragma unroll
                for (int i2 = 0; i2 < 8; ++i2)
                    bv.u[i2] = k_lds[bsel][rbase + i2][dcol];
                acc[dt] = __builtin_amdgcn_mfma_f32_16x16x32_bf16(ap, bv.v, acc[dt], 0, 0, 0);
            }
        }
    };

    // prologue: tile0 -> buf0 (immediate), tile1 issued into ldA
    issue(0, ldB);
    wtile(ldB, 0);
    if (pt == 0) patch(0);
    issue(1, ldA);
    __syncthreads();

    // main loop: 2 tiles per iteration, ONE barrier per tile.
    for (int tb = 0; tb < NTIL; tb += 2) {
        // even tile tb: regs ldA hold tile tb+1
        if (tb + 2 < NTIL) issue(tb + 2, ldB);
        compute(tb);
        wtile(ldA, (tb + 1) % 3);                 // tb+1 <= NTIL-1 always
        if (pt == tb + 1) patch((tb + 1) % 3);
        __syncthreads();
        // odd tile tb+1: regs ldB hold tile tb+2 (if any)
        if (tb + 3 < NTIL) issue(tb + 3, ldA);
        compute(tb + 1);
        if (tb + 2 < NTIL) {
            wtile(ldB, (tb + 2) % 3);
            if (pt == tb + 2) patch((tb + 2) % 3);
        }
        __syncthreads();
    }

    // ---- epilogue: O[head = lg*4+reg][dim = wave*128 + dt*16 + hd]
    float* po = part_o + ((size_t)(b * NC + c) * H) * LORA;
#pragma unroll
    for (int dt = 0; dt < 8; ++dt) {
        const int dim = wave * 128 + dt * 16 + hd;
        const int hb = lg * 4;
        po[(size_t)(hb + 0) * LORA + dim] = acc[dt][0];
        po[(size_t)(hb + 1) * LORA + dim] = acc[dt][1];
        po[(size_t)(hb + 2) * LORA + dim] = acc[dt][2];
        po[(size_t)(hb + 3) * LORA + dim] = acc[dt][3];
    }
    if (wave == 0 && lane < 16) {
        float* pml = part_ml + ((size_t)(b * NC + c) * H + lane) * 2;
        pml[0] = m_run;
        pml[1] = l_run;
    }
}

// ---------------- Kernel 5: combine partials -> o (LDS), fused v = o . W_UV
__global__ __launch_bounds__(256) void k_combine(
    const float* __restrict__ part_o, const float* __restrict__ part_ml,
    const float* __restrict__ W_UV, float* __restrict__ v) {
    const int b0 = blockIdx.x * 4, h = blockIdx.y, t = threadIdx.x;
    __shared__ float ml_s[4][NC][2];
    __shared__ float o_s[4][LORA]; // 8 KB
    for (int i = t; i < 4 * NC * 2; i += 256) {
        const int b2 = i / (NC * 2), rest = i % (NC * 2);
        const int c = rest >> 1, w = rest & 1;
        ml_s[b2][c][w] = part_ml[(((size_t)(b0 + b2) * NC + c) * H + h) * 2 + w];
    }
    __syncthreads();
    float m_b[4], inv_l[4];
#pragma unroll
    for (int b2 = 0; b2 < 4; ++b2) {
        float m = -INFINITY;
        for (int c = 0; c < NC; c++) m = fmaxf(m, ml_s[b2][c][0]);
        float l = 0.f;
        for (int c = 0; c < NC; c++) l += ml_s[b2][c][1] * __expf(ml_s[b2][c][0] - m);
        m_b[b2] = m;
        inv_l[b2] = 1.0f / l;
    }
    for (int i = t; i < 4 * LORA; i += 256) {
        const int b2 = i >> 9, li = i & 511;
        float acc = 0.f;
        for (int c = 0; c < NC; c++) {
            acc += part_o[(((size_t)(b0 + b2) * NC + c) * H + h) * LORA + li] *
                   __expf(ml_s[b2][c][0] - m_b[b2]);
        }
        o_s[b2][li] = acc * inv_l[b2];
    }
    __syncthreads();
    const int vi = t & 127, bp = t >> 7;
    float acc0 = 0.f, acc1 = 0.f;
    for (int l = 0; l < LORA; l += 4) {
        const float w0 = W_UV[(size_t)(l + 0) * (H * VH) + h * VH + vi];
        const float w1 = W_UV[(size_t)(l + 1) * (H * VH) + h * VH + vi];
        const float w2 = W_UV[(size_t)(l + 2) * (H * VH) + h * VH + vi];
        const float w3 = W_UV[(size_t)(l + 3) * (H * VH) + h * VH + vi];
        const float4 oa = *(const float4*)&o_s[bp * 2][l];
        const float4 ob = *(const float4*)&o_s[bp * 2 + 1][l];
        acc0 += oa.x * w0 + oa.y * w1 + oa.z * w2 + oa.w * w3;
        acc1 += ob.x * w0 + ob.y * w1 + ob.z * w2 + ob.w * w3;
    }
    v[(size_t)(b0 + bp * 2) * (H * VH) + h * VH + vi] = acc0;
    v[(size_t)(b0 + bp * 2 + 1) * (H * VH) + h * VH + vi] = acc1;
}

// ---------------- Kernel 6: out_part[ks] = V[:, k-slice] @ W_O[k-slice, :]
__global__ void k_out(const float* __restrict__ v, const float* __restrict__ W_O,
                      float* __restrict__ out_part) {
    const int dsl = blockIdx.x, ksl = blockIdx.y, t = threadIdx.x;
    const int d0 = dsl * 128, k0 = ksl * 128;
    __shared__ float vs[32][128];
    for (int i = t; i < 32 * 128; i += 256) {
        const int bi = i >> 7, kk = i & 127;
        vs[bi][kk] = v[(size_t)bi * DM + k0 + kk];
    }
    __syncthreads();
    const int dl = t & 127, bh = t >> 7;
    float acc[16];
#pragma unroll
    for (int i = 0; i < 16; i++) acc[i] = 0.f;
    for (int kk = 0; kk < 128; kk += 4) {
        const float w0 = W_O[(size_t)(k0 + kk + 0) * DM + d0 + dl];
        const float w1 = W_O[(size_t)(k0 + kk + 1) * DM + d0 + dl];
        const float w2 = W_O[(size_t)(k0 + kk + 2) * DM + d0 + dl];
        const float w3 = W_O[(size_t)(k0 + kk + 3) * DM + d0 + dl];
#pragma unroll
        for (int i = 0; i < 16; i++) {
            const float4 vv = *(const float4*)&vs[bh * 16 + i][kk];
            acc[i] += vv.x * w0 + vv.y * w1 + vv.z * w2 + vv.w * w3;
        }
    }
    float* op = out_part + (size_t)ksl * 32 * DM;
#pragma unroll
    for (int i = 0; i < 16; i++) op[(size_t)(bh * 16 + i) * DM + d0 + dl] = acc[i];
}

// ---------------- Kernel 7: reduce the 16 split-K partials
__global__ void k_out_reduce(const float* __restrict__ out_part, float* __restrict__ out) {
    const int idx = blockIdx.x * 256 + threadIdx.x;
    float4 acc = make_float4(0.f, 0.f, 0.f, 0.f);
    for (int ks = 0; ks < 16; ks++) {
        float4 p = *(const float4*)(out_part + (size_t)ks * (32 * DM) + (size_t)idx * 4);
        acc.x += p.x; acc.y += p.y; acc.z += p.z; acc.w += p.w;
    }
    *(float4*)(out + (size_t)idx * 4) = acc;
}

extern "C" void kernel_launch(void* const* d_in, const int* in_sizes, int n_in,
                              void* d_out, int out_size, void* d_ws, size_t ws_size,
                              hipStream_t stream) {
    const float* q_c        = (const float*)d_in[0];
    const float* k_c_normed = (const float*)d_in[1];
    const float* k_pe       = (const float*)d_in[2];
    const float* kv_c_cache = (const float*)d_in[3];
    const float* k_pe_cache = (const float*)d_in[4];
    const float* W_UQ       = (const float*)d_in[5];
    const float* W_UK       = (const float*)d_in[6];
    const float* W_QR       = (const float*)d_in[7];
    const float* W_UV       = (const float*)d_in[8];
    const float* W_O        = (const float*)d_in[9];
    const int*   pos        = (const int*)d_in[10];

    float* ws = (float*)d_ws;
    float* q_t       = ws;                        // 65536 floats
    float* qbf_f     = q_t + 65536;               // 147456 floats reserved for q_bf
    ushort* q_bf     = (ushort*)qbf_f;            // [32][16][576] bf16
    float* kpe_rot   = qbf_f + 147456;            // 2048
    float* part_o    = kpe_rot + 2048;            // 32*16*16*512 = 4194304
    float* part_ml   = part_o + (size_t)B * NC * H * LORA;   // 16384
    float* v         = part_ml + (size_t)B * NC * H * 2;     // 65536
    float* out_part  = v + 65536;                 // 1048576
    float* proj_part = out_part + (size_t)16 * 32 * DM;      // 2359296

    k_proj_part<<<dim3(NKS, 12), 256, 0, stream>>>(q_c, W_UQ, W_QR, proj_part);
    k_finalize<<<81, 256, 0, stream>>>(proj_part, k_pe, pos, q_t, q_bf, kpe_rot);
    k_qnope<<<dim3(8, 16), 256, 0, stream>>>(q_t, W_UK, q_bf);
    k_flash<<<B * NC, 256, 0, stream>>>(q_bf, kv_c_cache, k_pe_cache,
                                        k_c_normed, kpe_rot, pos, part_o, part_ml);
    k_combine<<<dim3(8, 16), 256, 0, stream>>>(part_o, part_ml, W_UV, v);
    k_out<<<dim3(16, 16), 256, 0, stream>>>(v, W_O, out_part);
    k_out_reduce<<<64, 256, 0, stream>>>(out_part, (float*)d_out);
}